// Round 3
// baseline (587.983 us; speedup 1.0000x reference)
//
#include <hip/hip_runtime.h>
#include <math.h>

#define EPSV 1e-6f
#define NTOK 8192
#define NE   16384
#define DIM  256

using short8 = __attribute__((ext_vector_type(8))) short;
using f32x4v = __attribute__((ext_vector_type(4))) float;

__device__ __forceinline__ unsigned short f2bf(float v) {
    unsigned int u = __float_as_uint(v);
    u += 0x7fffu + ((u >> 16) & 1u);   // RNE
    return (unsigned short)(u >> 16);
}
__device__ __forceinline__ float bf2f(unsigned short h) {
    return __uint_as_float(((unsigned int)h) << 16);
}

__device__ __forceinline__ void gload_lds16(const void* g, void* s) {
    __builtin_amdgcn_global_load_lds(
        (const __attribute__((address_space(1))) void*)g,
        (__attribute__((address_space(3))) void*)s, 16, 0, 0);
}

// split 8 consecutive fp32 into bf16 hi/lo fragments
__device__ __forceinline__ void split8(const float4 a, const float4 b,
                                       short8& h, short8& l) {
    float f[8] = {a.x, a.y, a.z, a.w, b.x, b.y, b.z, b.w};
#pragma unroll
    for (int j = 0; j < 8; ++j) {
        unsigned short hh = f2bf(f[j]);
        h[j] = (short)hh;
        l[j] = (short)f2bf(f[j] - bf2f(hh));
    }
}

// ---------------------------------------------------------------- K0a:
// z (b,c,h,w) -> z_flat (tok, c) fp32 + bf16 hi/lo split.
__global__ __launch_bounds__(256) void k0a_transpose(
    const float* __restrict__ zin, float* __restrict__ z_flat,
    unsigned short* __restrict__ zh, unsigned short* __restrict__ zl) {
    __shared__ float tile[64][65];
    const int tid = threadIdx.x;
    const int yx0 = blockIdx.x * 64, c0 = blockIdx.y * 64, b = blockIdx.z;
    const int sub = tid >> 6, ln = tid & 63;
#pragma unroll
    for (int j = 0; j < 16; ++j) {
        int cl = j * 4 + sub;
        tile[cl][ln] = zin[((size_t)(b * 256 + c0 + cl) << 10) + yx0 + ln];
    }
    __syncthreads();
#pragma unroll
    for (int j = 0; j < 16; ++j) {
        int tl = j * 4 + sub;
        float v = tile[ln][tl];
        size_t o = (size_t)(b * 1024 + yx0 + tl) * 256 + c0 + ln;
        z_flat[o] = v;
        unsigned short h = f2bf(v);
        zh[o] = h;
        zl[o] = f2bf(v - bf2f(h));
    }
}

// ---------------------------------------------------------------- K0b:
// sz[t] = sum(z^2) per token, fp64 accumulate.
__global__ __launch_bounds__(256) void k0b_sz(const float* __restrict__ z_flat,
                                              float* __restrict__ sz) {
    const int w = threadIdx.x >> 6, lane = threadIdx.x & 63;
    const int t = blockIdx.x * 4 + w;
    const float4 v = *(const float4*)(z_flat + (size_t)t * 256 + lane * 4);
    double s = (double)v.x * v.x + (double)v.y * v.y + (double)v.z * v.z +
               (double)v.w * v.w;
#pragma unroll
    for (int m = 1; m < 64; m <<= 1) s += __shfl_xor(s, m);
    if (lane == 0) sz[t] = (float)s;
}

// ---------------------------------------------------------------- K0pre:
// split W (256x256 fp32) into bf16 hi/lo.
__global__ __launch_bounds__(256) void k0pre(const float* __restrict__ Wm,
                                             unsigned short* __restrict__ wh,
                                             unsigned short* __restrict__ wl) {
    const int i = (blockIdx.x * 256 + threadIdx.x) * 4;
    const float4 v = *(const float4*)(Wm + i);
    float f[4] = {v.x, v.y, v.z, v.w};
#pragma unroll
    for (int j = 0; j < 4; ++j) {
        unsigned short h = f2bf(f[j]);
        wh[i + j] = h;
        wl[i + j] = f2bf(f[j] - bf2f(h));
    }
}

// ---------------------------------------------------------------- K0c:
// emb = codebook @ W.T via 4-term bf16x2 MFMA (fp32-class accuracy).
// Grid (128, 2): 128x128 tile, 4 waves in 2x2 (64x64). K-chunks of 64.
// LDS: cbS fp32 (32KB, split in-register) + whS/wlS bf16 (16KB each).
__global__ __launch_bounds__(256, 2) void k0c_emb(
    const float* __restrict__ cb, const unsigned short* __restrict__ wh,
    const unsigned short* __restrict__ wl, float* __restrict__ emb,
    unsigned short* __restrict__ eh, unsigned short* __restrict__ el) {
    __shared__ char smemC[65536];
    const int tid = threadIdx.x;
    const int w = tid >> 6, lane = tid & 63;
    const int quad = lane >> 4, lr = lane & 15;
    const int wr = w & 1, wc = w >> 1;
    const int n0 = blockIdx.x * 128, c0 = blockIdx.y * 128;

    f32x4v acc[4][4];
#pragma unroll
    for (int mt = 0; mt < 4; ++mt)
#pragma unroll
        for (int nt = 0; nt < 4; ++nt)
            acc[mt][nt] = (f32x4v){0.f, 0.f, 0.f, 0.f};

    for (int kc = 0; kc < 4; ++kc) {
        __syncthreads();
#pragma unroll
        for (int i = 0; i < 16; ++i) {
            int s = i * 4 + w;           // wave-uniform segment 0..63
            int u = s * 64 + lane;       // global unit 0..4095
            const void* g;
            if (s < 32) {                // cbS: [kg(16)][row(128)] fp32x4
                int kg = u >> 7, row = u & 127;
                g = cb + (size_t)(n0 + row) * 256 + kc * 64 + kg * 4;
            } else if (s < 48) {         // whS: [kg(8)][row(128)] bf16x8
                int u1 = u - 2048;
                int kg = u1 >> 7, row = u1 & 127;
                g = wh + (size_t)(c0 + row) * 256 + kc * 64 + kg * 8;
            } else {                     // wlS
                int u2 = u - 3072;
                int kg = u2 >> 7, row = u2 & 127;
                g = wl + (size_t)(c0 + row) * 256 + kc * 64 + kg * 8;
            }
            gload_lds16(g, smemC + ((size_t)u << 4));
        }
        __syncthreads();
#pragma unroll
        for (int ks = 0; ks < 2; ++ks) {
            short8 Ah[4], Al[4], Bh[4], Bl[4];
#pragma unroll
            for (int mt = 0; mt < 4; ++mt) {
                int m = wr * 64 + mt * 16 + lr;
                int kg2 = ks * 8 + quad * 2;
                float4 f0 = *(const float4*)(smemC + (((size_t)kg2 * 128 + m) << 4));
                float4 f1 = *(const float4*)(smemC + ((((size_t)kg2 + 1) * 128 + m) << 4));
                split8(f0, f1, Ah[mt], Al[mt]);
            }
#pragma unroll
            for (int nt = 0; nt < 4; ++nt) {
                int n = wc * 64 + nt * 16 + lr;
                int ku = (ks * 4 + quad) * 128 + n;
                Bh[nt] = *(const short8*)(smemC + (((size_t)2048 + ku) << 4));
                Bl[nt] = *(const short8*)(smemC + (((size_t)3072 + ku) << 4));
            }
#pragma unroll
            for (int mt = 0; mt < 4; ++mt)
#pragma unroll
                for (int nt = 0; nt < 4; ++nt) {
                    f32x4v a = acc[mt][nt];
                    a = __builtin_amdgcn_mfma_f32_16x16x32_bf16(Ah[mt], Bh[nt], a, 0, 0, 0);
                    a = __builtin_amdgcn_mfma_f32_16x16x32_bf16(Ah[mt], Bl[nt], a, 0, 0, 0);
                    a = __builtin_amdgcn_mfma_f32_16x16x32_bf16(Al[mt], Bh[nt], a, 0, 0, 0);
                    a = __builtin_amdgcn_mfma_f32_16x16x32_bf16(Al[mt], Bl[nt], a, 0, 0, 0);
                    acc[mt][nt] = a;
                }
        }
    }
#pragma unroll
    for (int mt = 0; mt < 4; ++mt)
#pragma unroll
        for (int rr = 0; rr < 4; ++rr) {
            int row = n0 + wr * 64 + mt * 16 + quad * 4 + rr;
#pragma unroll
            for (int nt = 0; nt < 4; ++nt) {
                int col = c0 + wc * 64 + nt * 16 + lr;
                size_t o = (size_t)row * 256 + col;
                float v = acc[mt][nt][rr];
                emb[o] = v;
                unsigned short h = f2bf(v);
                eh[o] = h;
                el[o] = f2bf(v - bf2f(h));
            }
        }
}

// ---------------------------------------------------------------- K0d:
// se[n] = sum(emb^2) per code row, fp64 accumulate.
__global__ __launch_bounds__(256) void k0d_se(const float* __restrict__ emb,
                                              float* __restrict__ se) {
    const int w = threadIdx.x >> 6, lane = threadIdx.x & 63;
    const int n = blockIdx.x * 4 + w;
    const float4 v = *(const float4*)(emb + (size_t)n * 256 + lane * 4);
    double s = (double)v.x * v.x + (double)v.y * v.y + (double)v.z * v.z +
               (double)v.w * v.w;
#pragma unroll
    for (int m = 1; m < 64; m <<= 1) s += __shfl_xor(s, m);
    if (lane == 0) se[n] = (float)s;
}

// ---------------------------------------------------------------- K1:
// Fused bf16x2 (3-term) MFMA GEMM + argmin. A register-resident;
// B (eh,el) streamed straight to registers from L1/L2 — NO LDS, NO barriers.
// Grid (64, 8). 4 waves x 32 rows. Chunk = 32 codes.
__global__ __launch_bounds__(256, 2) void k1_dist_argmin(
    const unsigned short* __restrict__ zh, const unsigned short* __restrict__ zl,
    const unsigned short* __restrict__ eh, const unsigned short* __restrict__ el,
    const float* __restrict__ sz, const float* __restrict__ se,
    float* __restrict__ pval, int* __restrict__ pidx) {
    const int tid = threadIdx.x;
    const int w = tid >> 6, lane = tid & 63;
    const int quad = lane >> 4, lr = lane & 15;
    const int tokBase = blockIdx.x * 128;
    const int rowBase = tokBase + w * 32;
    const int slab = blockIdx.y;
    const int slabBase = slab * 2048;

    // A fragments resident for the whole kernel (128 VGPRs)
    short8 Ah[2][8], Al[2][8];
#pragma unroll
    for (int mt = 0; mt < 2; ++mt)
#pragma unroll
        for (int ks = 0; ks < 8; ++ks) {
            size_t o = (size_t)(rowBase + mt * 16 + lr) * 256 + ks * 32 + quad * 8;
            Ah[mt][ks] = *(const short8*)(zh + o);
            Al[mt][ks] = *(const short8*)(zl + o);
        }

    float szr[2][4];
#pragma unroll
    for (int mt = 0; mt < 2; ++mt)
#pragma unroll
        for (int rr = 0; rr < 4; ++rr)
            szr[mt][rr] = sz[rowBase + mt * 16 + quad * 4 + rr];

    float minv[2][4];
    int mini[2][4];
#pragma unroll
    for (int mt = 0; mt < 2; ++mt)
#pragma unroll
        for (int rr = 0; rr < 4; ++rr) {
            minv[mt][rr] = INFINITY;
            mini[mt][rr] = 0;
        }

    // lane-fixed B pointers: row = slabBase + lr (nt=1 adds 16 rows = 8192 B),
    // byte offset per ks = ks*64, per chunk += 32 rows = 16384 B.
    const char* pH = (const char*)eh + (((size_t)(slabBase + lr)) << 9) + (quad << 4);
    const char* pL = (const char*)el + (((size_t)(slabBase + lr)) << 9) + (quad << 4);
    const float* pSe = se + slabBase + lr;

    for (int ch = 0; ch < 64; ++ch) {
        const float se0 = pSe[0];
        const float se1 = pSe[16];
        f32x4v acc[2][2];
#pragma unroll
        for (int mt = 0; mt < 2; ++mt)
#pragma unroll
            for (int nt = 0; nt < 2; ++nt)
                acc[mt][nt] = (f32x4v){0.f, 0.f, 0.f, 0.f};

#pragma unroll
        for (int ks = 0; ks < 8; ++ks) {
            short8 bh0 = *(const short8*)(pH + ks * 64);
            short8 bh1 = *(const short8*)(pH + 8192 + ks * 64);
            short8 bl0 = *(const short8*)(pL + ks * 64);
            short8 bl1 = *(const short8*)(pL + 8192 + ks * 64);
#pragma unroll
            for (int mt = 0; mt < 2; ++mt) {
                f32x4v a0 = acc[mt][0], a1 = acc[mt][1];
                a0 = __builtin_amdgcn_mfma_f32_16x16x32_bf16(Ah[mt][ks], bh0, a0, 0, 0, 0);
                a0 = __builtin_amdgcn_mfma_f32_16x16x32_bf16(Ah[mt][ks], bl0, a0, 0, 0, 0);
                a0 = __builtin_amdgcn_mfma_f32_16x16x32_bf16(Al[mt][ks], bh0, a0, 0, 0, 0);
                a1 = __builtin_amdgcn_mfma_f32_16x16x32_bf16(Ah[mt][ks], bh1, a1, 0, 0, 0);
                a1 = __builtin_amdgcn_mfma_f32_16x16x32_bf16(Ah[mt][ks], bl1, a1, 0, 0, 0);
                a1 = __builtin_amdgcn_mfma_f32_16x16x32_bf16(Al[mt][ks], bh1, a1, 0, 0, 0);
                acc[mt][0] = a0;
                acc[mt][1] = a1;
            }
        }

        // d = fl(fl(sz+se) - 2*dot); strict < keeps lowest index
        const int colBase = slabBase + ch * 32;
#pragma unroll
        for (int nt = 0; nt < 2; ++nt) {
            const int colg = colBase + nt * 16 + lr;
            const float sec = nt ? se1 : se0;
#pragma unroll
            for (int mt = 0; mt < 2; ++mt)
#pragma unroll
                for (int rr = 0; rr < 4; ++rr) {
                    float d = __fsub_rn(__fadd_rn(szr[mt][rr], sec),
                                        2.0f * acc[mt][nt][rr]);
                    if (d < minv[mt][rr]) {
                        minv[mt][rr] = d;
                        mini[mt][rr] = colg;
                    }
                }
        }
        pH += 16384;
        pL += 16384;
        pSe += 32;
    }

    // reduce across the 16 lanes (lr) that share each output row
#pragma unroll
    for (int st = 1; st < 16; st <<= 1) {
#pragma unroll
        for (int mt = 0; mt < 2; ++mt)
#pragma unroll
            for (int rr = 0; rr < 4; ++rr) {
                float ov = __shfl_xor(minv[mt][rr], st);
                int oi = __shfl_xor(mini[mt][rr], st);
                if (ov < minv[mt][rr] ||
                    (ov == minv[mt][rr] && oi < mini[mt][rr])) {
                    minv[mt][rr] = ov;
                    mini[mt][rr] = oi;
                }
            }
    }
    if (lr == 0) {
#pragma unroll
        for (int mt = 0; mt < 2; ++mt)
#pragma unroll
            for (int rr = 0; rr < 4; ++rr) {
                int row = rowBase + mt * 16 + quad * 4 + rr;
                pval[(size_t)row * 8 + slab] = minv[mt][rr];
                pidx[(size_t)row * 8 + slab] = mini[mt][rr];
            }
    }
}

// ---------------------------------------------------------------- K3a:
// per-token: reduce 8 slab partials (parallel across lanes) -> final index;
// rotation scalars alpha/beta; per-block loss partial.
__global__ __launch_bounds__(256) void k3a_token(
    const float* __restrict__ z_flat, const float* __restrict__ emb,
    const float* __restrict__ pval, const int* __restrict__ pidx,
    float* __restrict__ alpha, float* __restrict__ beta,
    int* __restrict__ idxf, float* __restrict__ out,
    float* __restrict__ lpart) {
    __shared__ float red[4];
    const int w = threadIdx.x >> 6, lane = threadIdx.x & 63;
    const int t = blockIdx.x * 4 + w;

    float bv = INFINITY;
    int bi = 0x7fffffff;
    if (lane < 8) {
        bv = pval[(size_t)t * 8 + lane];
        bi = pidx[(size_t)t * 8 + lane];
    }
#pragma unroll
    for (int st = 1; st < 8; st <<= 1) {
        float ov = __shfl_xor(bv, st);
        int oi = __shfl_xor(bi, st);
        if (ov < bv || (ov == bv && oi < bi)) { bv = ov; bi = oi; }
    }
    const int best = __shfl(bi, 0);

    const float4 zv = *(const float4*)(z_flat + (size_t)t * 256 + lane * 4);
    const float4 ev = *(const float4*)(emb + (size_t)best * 256 + lane * 4);
    float szs = zv.x * zv.x + zv.y * zv.y + zv.z * zv.z + zv.w * zv.w;
    float ses = ev.x * ev.x + ev.y * ev.y + ev.z * ev.z + ev.w * ev.w;
    float zes = zv.x * ev.x + zv.y * ev.y + zv.z * ev.z + zv.w * ev.w;
    float dx = zv.x - ev.x, dy = zv.y - ev.y, dz = zv.z - ev.z, dw = zv.w - ev.w;
    float sqs = dx * dx + dy * dy + dz * dz + dw * dw;
#pragma unroll
    for (int m = 1; m < 64; m <<= 1) {
        szs += __shfl_xor(szs, m);
        ses += __shfl_xor(ses, m);
        zes += __shfl_xor(zes, m);
        sqs += __shfl_xor(sqs, m);
    }
    if (lane == 0) {
        float ns = sqrtf(szs), nt = sqrtf(ses);
        float inv_s = 1.0f / (ns + EPSV);
        float inv_t = 1.0f / (nt + EPSV);
        float s2 = szs * inv_s;                      // z . u
        float su = szs * inv_s * inv_s;
        float sq = ses * inv_t * inv_t;
        float uq = zes * inv_s * inv_t;
        float nw = sqrtf(su + sq + 2.0f * uq);
        float inv_w = 1.0f / (nw + EPSV);
        float s1 = (s2 + zes * inv_t) * inv_w;       // z . w_
        float scale = nt * inv_s;
        float a = scale * (1.0f - 2.0f * s1 * inv_w * inv_s);
        float bb = scale * inv_t * 2.0f * (s2 - s1 * inv_w);
        alpha[t] = a;
        beta[t] = bb;
        idxf[t] = best;
        out[2097153 + t] = (float)best;
        red[w] = sqs;
    }
    __syncthreads();
    if (threadIdx.x == 0)
        lpart[blockIdx.x] = red[0] + red[1] + red[2] + red[3];
}

// ---------------------------------------------------------------- K4: loss
__global__ __launch_bounds__(256) void k4_loss(float* __restrict__ out,
                                               const float* __restrict__ lpart) {
    __shared__ float red[4];
    const int tid = threadIdx.x;
    float s = 0.0f;
    for (int i = tid; i < 2048; i += 256) s += lpart[i];
#pragma unroll
    for (int m = 1; m < 64; m <<= 1) s += __shfl_xor(s, m);
    if ((tid & 63) == 0) red[tid >> 6] = s;
    __syncthreads();
    if (tid == 0)
        out[2097152] = 1.25f * (red[0] + red[1] + red[2] + red[3]) *
                       (1.0f / 2097152.0f);
}

// ---------------------------------------------------------------- K3b:
// z_q[b][c][yx] = alpha[t]*z[b][c][yx] + beta[t]*emb[idx[t]][c]
__global__ __launch_bounds__(256) void k3b_zq(
    const float* __restrict__ zin, const float* __restrict__ emb,
    const float* __restrict__ alpha, const float* __restrict__ beta,
    const int* __restrict__ idxf, float* __restrict__ out) {
    const int i = blockIdx.x * 256 + threadIdx.x;
    const int c = (i >> 10) & 255;
    const int t = ((i >> 18) << 10) | (i & 1023);
    out[i] = alpha[t] * zin[i] + beta[t] * emb[(size_t)idxf[t] * 256 + c];
}

// ----------------------------------------------------------------
extern "C" void kernel_launch(void* const* d_in, const int* in_sizes, int n_in,
                              void* d_out, int out_size, void* d_ws,
                              size_t ws_size, hipStream_t stream) {
    (void)in_sizes; (void)n_in; (void)out_size; (void)ws_size;
    const float* zin = (const float*)d_in[0];
    const float* cb  = (const float*)d_in[1];
    const float* Wm  = (const float*)d_in[2];
    float* out = (float*)d_out;
    char* ws = (char*)d_ws;

    float*          z_flat = (float*)(ws + 0);                     //  8 MB
    unsigned short* zh     = (unsigned short*)(ws + 8388608);      //  4 MB
    unsigned short* zl     = (unsigned short*)(ws + 12582912);     //  4 MB
    float*          emb    = (float*)(ws + 16777216);              // 16 MB
    unsigned short* eh     = (unsigned short*)(ws + 33554432);     //  8 MB
    unsigned short* el     = (unsigned short*)(ws + 41943040);     //  8 MB
    float*          sz     = (float*)(ws + 50331648);              // 32 KB
    float*          se     = (float*)(ws + 50364416);              // 64 KB
    float*          pval   = (float*)(ws + 50429952);              // 256 KB
    int*            pidx   = (int*)(ws + 50692096);                // 256 KB
    float*          alpha  = (float*)(ws + 50954240);              // 32 KB
    float*          beta   = (float*)(ws + 50987008);              // 32 KB
    int*            idxf   = (int*)(ws + 51019776);                // 32 KB
    float*          lpart  = (float*)(ws + 51052544);              //  8 KB
    unsigned short* wh     = (unsigned short*)(ws + 51060736);     // 128 KB
    unsigned short* wl     = (unsigned short*)(ws + 51191808);     // 128 KB

    k0a_transpose<<<dim3(16, 4, 8), 256, 0, stream>>>(zin, z_flat, zh, zl);
    k0b_sz<<<2048, 256, 0, stream>>>(z_flat, sz);
    k0pre<<<64, 256, 0, stream>>>(Wm, wh, wl);
    k0c_emb<<<dim3(128, 2), 256, 0, stream>>>(cb, wh, wl, emb, eh, el);
    k0d_se<<<4096, 256, 0, stream>>>(emb, se);
    k1_dist_argmin<<<dim3(64, 8), 256, 0, stream>>>(zh, zl, eh, el, sz, se,
                                                    pval, pidx);
    k3a_token<<<2048, 256, 0, stream>>>(z_flat, emb, pval, pidx, alpha, beta,
                                        idxf, out, lpart);
    k4_loss<<<1, 256, 0, stream>>>(out, lpart);
    k3b_zq<<<8192, 256, 0, stream>>>(zin, emb, alpha, beta, idxf, out);
}

// Round 4
// 309.206 us; speedup vs baseline: 1.9016x; 1.9016x over previous
//
#include <hip/hip_runtime.h>
#include <math.h>

#define EPSV 1e-6f
#define NTOK 8192
#define NE   16384
#define DIM  256

using short8 = __attribute__((ext_vector_type(8))) short;
using f32x4v = __attribute__((ext_vector_type(4))) float;
using f32x16 = __attribute__((ext_vector_type(16))) float;

__device__ __forceinline__ unsigned short f2bf(float v) {
    unsigned int u = __float_as_uint(v);
    u += 0x7fffu + ((u >> 16) & 1u);   // RNE
    return (unsigned short)(u >> 16);
}
__device__ __forceinline__ float bf2f(unsigned short h) {
    return __uint_as_float(((unsigned int)h) << 16);
}

__device__ __forceinline__ void gload_lds16(const void* g, void* s) {
    __builtin_amdgcn_global_load_lds(
        (const __attribute__((address_space(1))) void*)g,
        (__attribute__((address_space(3))) void*)s, 16, 0, 0);
}

// split 8 consecutive fp32 into bf16 hi/lo fragments
__device__ __forceinline__ void split8(const float4 a, const float4 b,
                                       short8& h, short8& l) {
    float f[8] = {a.x, a.y, a.z, a.w, b.x, b.y, b.z, b.w};
#pragma unroll
    for (int j = 0; j < 8; ++j) {
        unsigned short hh = f2bf(f[j]);
        h[j] = (short)hh;
        l[j] = (short)f2bf(f[j] - bf2f(hh));
    }
}

// ---------------------------------------------------------------- K0a:
// z (b,c,h,w) -> z_flat (tok, c) fp32 + bf16 hi/lo split.
__global__ __launch_bounds__(256) void k0a_transpose(
    const float* __restrict__ zin, float* __restrict__ z_flat,
    unsigned short* __restrict__ zh, unsigned short* __restrict__ zl) {
    __shared__ float tile[64][65];
    const int tid = threadIdx.x;
    const int yx0 = blockIdx.x * 64, c0 = blockIdx.y * 64, b = blockIdx.z;
    const int sub = tid >> 6, ln = tid & 63;
#pragma unroll
    for (int j = 0; j < 16; ++j) {
        int cl = j * 4 + sub;
        tile[cl][ln] = zin[((size_t)(b * 256 + c0 + cl) << 10) + yx0 + ln];
    }
    __syncthreads();
#pragma unroll
    for (int j = 0; j < 16; ++j) {
        int tl = j * 4 + sub;
        float v = tile[ln][tl];
        size_t o = (size_t)(b * 1024 + yx0 + tl) * 256 + c0 + ln;
        z_flat[o] = v;
        unsigned short h = f2bf(v);
        zh[o] = h;
        zl[o] = f2bf(v - bf2f(h));
    }
}

// ---------------------------------------------------------------- K0b:
// sz[t] = sum(z^2) per token, fp64 accumulate.
__global__ __launch_bounds__(256) void k0b_sz(const float* __restrict__ z_flat,
                                              float* __restrict__ sz) {
    const int w = threadIdx.x >> 6, lane = threadIdx.x & 63;
    const int t = blockIdx.x * 4 + w;
    const float4 v = *(const float4*)(z_flat + (size_t)t * 256 + lane * 4);
    double s = (double)v.x * v.x + (double)v.y * v.y + (double)v.z * v.z +
               (double)v.w * v.w;
#pragma unroll
    for (int m = 1; m < 64; m <<= 1) s += __shfl_xor(s, m);
    if (lane == 0) sz[t] = (float)s;
}

// ---------------------------------------------------------------- K0pre:
// split W (256x256 fp32) into bf16 hi/lo.
__global__ __launch_bounds__(256) void k0pre(const float* __restrict__ Wm,
                                             unsigned short* __restrict__ wh,
                                             unsigned short* __restrict__ wl) {
    const int i = (blockIdx.x * 256 + threadIdx.x) * 4;
    const float4 v = *(const float4*)(Wm + i);
    float f[4] = {v.x, v.y, v.z, v.w};
#pragma unroll
    for (int j = 0; j < 4; ++j) {
        unsigned short h = f2bf(f[j]);
        wh[i + j] = h;
        wl[i + j] = f2bf(f[j] - bf2f(h));
    }
}

// ---------------------------------------------------------------- K0c:
// emb = codebook @ W.T via 4-term bf16x2 MFMA (fp32-class accuracy).
__global__ __launch_bounds__(256, 2) void k0c_emb(
    const float* __restrict__ cb, const unsigned short* __restrict__ wh,
    const unsigned short* __restrict__ wl, float* __restrict__ emb,
    unsigned short* __restrict__ eh, unsigned short* __restrict__ el) {
    __shared__ char smemC[65536];
    const int tid = threadIdx.x;
    const int w = tid >> 6, lane = tid & 63;
    const int quad = lane >> 4, lr = lane & 15;
    const int wr = w & 1, wc = w >> 1;
    const int n0 = blockIdx.x * 128, c0 = blockIdx.y * 128;

    f32x4v acc[4][4];
#pragma unroll
    for (int mt = 0; mt < 4; ++mt)
#pragma unroll
        for (int nt = 0; nt < 4; ++nt)
            acc[mt][nt] = (f32x4v){0.f, 0.f, 0.f, 0.f};

    for (int kc = 0; kc < 4; ++kc) {
        __syncthreads();
#pragma unroll
        for (int i = 0; i < 16; ++i) {
            int s = i * 4 + w;           // wave-uniform segment 0..63
            int u = s * 64 + lane;       // global unit 0..4095
            const void* g;
            if (s < 32) {                // cbS: [kg(16)][row(128)] fp32x4
                int kg = u >> 7, row = u & 127;
                g = cb + (size_t)(n0 + row) * 256 + kc * 64 + kg * 4;
            } else if (s < 48) {         // whS: [kg(8)][row(128)] bf16x8
                int u1 = u - 2048;
                int kg = u1 >> 7, row = u1 & 127;
                g = wh + (size_t)(c0 + row) * 256 + kc * 64 + kg * 8;
            } else {                     // wlS
                int u2 = u - 3072;
                int kg = u2 >> 7, row = u2 & 127;
                g = wl + (size_t)(c0 + row) * 256 + kc * 64 + kg * 8;
            }
            gload_lds16(g, smemC + ((size_t)u << 4));
        }
        __syncthreads();
#pragma unroll
        for (int ks = 0; ks < 2; ++ks) {
            short8 Ah[4], Al[4], Bh[4], Bl[4];
#pragma unroll
            for (int mt = 0; mt < 4; ++mt) {
                int m = wr * 64 + mt * 16 + lr;
                int kg2 = ks * 8 + quad * 2;
                float4 f0 = *(const float4*)(smemC + (((size_t)kg2 * 128 + m) << 4));
                float4 f1 = *(const float4*)(smemC + ((((size_t)kg2 + 1) * 128 + m) << 4));
                split8(f0, f1, Ah[mt], Al[mt]);
            }
#pragma unroll
            for (int nt = 0; nt < 4; ++nt) {
                int n = wc * 64 + nt * 16 + lr;
                int ku = (ks * 4 + quad) * 128 + n;
                Bh[nt] = *(const short8*)(smemC + (((size_t)2048 + ku) << 4));
                Bl[nt] = *(const short8*)(smemC + (((size_t)3072 + ku) << 4));
            }
#pragma unroll
            for (int mt = 0; mt < 4; ++mt)
#pragma unroll
                for (int nt = 0; nt < 4; ++nt) {
                    f32x4v a = acc[mt][nt];
                    a = __builtin_amdgcn_mfma_f32_16x16x32_bf16(Ah[mt], Bh[nt], a, 0, 0, 0);
                    a = __builtin_amdgcn_mfma_f32_16x16x32_bf16(Ah[mt], Bl[nt], a, 0, 0, 0);
                    a = __builtin_amdgcn_mfma_f32_16x16x32_bf16(Al[mt], Bh[nt], a, 0, 0, 0);
                    a = __builtin_amdgcn_mfma_f32_16x16x32_bf16(Al[mt], Bl[nt], a, 0, 0, 0);
                    acc[mt][nt] = a;
                }
        }
    }
#pragma unroll
    for (int mt = 0; mt < 4; ++mt)
#pragma unroll
        for (int rr = 0; rr < 4; ++rr) {
            int row = n0 + wr * 64 + mt * 16 + quad * 4 + rr;
#pragma unroll
            for (int nt = 0; nt < 4; ++nt) {
                int col = c0 + wc * 64 + nt * 16 + lr;
                size_t o = (size_t)row * 256 + col;
                float v = acc[mt][nt][rr];
                emb[o] = v;
                unsigned short h = f2bf(v);
                eh[o] = h;
                el[o] = f2bf(v - bf2f(h));
            }
        }
}

// ---------------------------------------------------------------- K0d:
// se[n] = sum(emb^2) per code row, fp64 accumulate.
__global__ __launch_bounds__(256) void k0d_se(const float* __restrict__ emb,
                                              float* __restrict__ se) {
    const int w = threadIdx.x >> 6, lane = threadIdx.x & 63;
    const int n = blockIdx.x * 4 + w;
    const float4 v = *(const float4*)(emb + (size_t)n * 256 + lane * 4);
    double s = (double)v.x * v.x + (double)v.y * v.y + (double)v.z * v.z +
               (double)v.w * v.w;
#pragma unroll
    for (int m = 1; m < 64; m <<= 1) s += __shfl_xor(s, m);
    if (lane == 0) se[n] = (float)s;
}

// ---------------------------------------------------------------- K1:
// Fused bf16x2 (3-term) 32x32x16-MFMA GEMM + argmin.
// R2 structure (LDS dbuf + global_load_lds prefetch), 32x32 shape, and
// XOR-immediate B addressing to cut VALU.
// Grid (NTOK/128, 8 slabs). 4 waves; wave w owns rows [tokBase+w*32,+32).
// A frags register-resident: 16 ks x hi/lo = 128 VGPRs.
// LDS layout (per 16KB plane, 16B units): unit(c,kg) = c*32 + (kg^c).
// Read addr factors as BASE ^ (ks*32):
//   byte = c*512 + ((ks*2+half)^c)*16
//        = [c*512 + (half^(c&1))*16 + ((c&30)*16)] ^ (ks*32)
//   (bits: c*512 -> 9+, half-term -> bit4, (c&30)*16 -> bits5-8, ks*32 -> 5-8)
// Bank balance: 256 dwords spread 8/bank exactly -> 0 conflicts.
__global__ __launch_bounds__(256, 2) void k1_dist_argmin(
    const unsigned short* __restrict__ zh, const unsigned short* __restrict__ zl,
    const unsigned short* __restrict__ eh, const unsigned short* __restrict__ el,
    const float* __restrict__ sz, const float* __restrict__ se,
    float* __restrict__ pval, int* __restrict__ pidx) {
    __shared__ char smem[65536];       // 2 x 32 KB double buffer
    const int tid = threadIdx.x;
    const int w = tid >> 6, lane = tid & 63;
    const int col = lane & 31, half = lane >> 5;
    const int tokBase = blockIdx.x * 128;
    const int rowBase = tokBase + w * 32;
    const int slab = blockIdx.y;
    const int slabBase = slab * 2048;

    // A fragments: A[m=lane&31][k=half*8+j] per 16-k step. 128 VGPRs.
    short8 Ah[16], Al[16];
#pragma unroll
    for (int ks = 0; ks < 16; ++ks) {
        size_t o = (size_t)(rowBase + col) * 256 + ks * 16 + half * 8;
        Ah[ks] = *(const short8*)(zh + o);
        Al[ks] = *(const short8*)(zl + o);
    }

    // sz per C-register row: row(r) = (r&3) + 8*(r>>2) + 4*half
    float szrow[16];
#pragma unroll
    for (int r = 0; r < 16; ++r)
        szrow[r] = sz[rowBase + (r & 3) + 8 * (r >> 2) + 4 * half];

    float minv[16];
    int mini[16];
#pragma unroll
    for (int r = 0; r < 16; ++r) {
        minv[r] = INFINITY;
        mini[r] = 0;
    }

    const int BASE = col * 512 + ((half ^ (col & 1)) << 4) + ((col & 30) << 4);

    // stage chunk `ch` (32 codes x 256 k, hi+lo) into buffer `buf`
    auto stage = [&](int buf, int ch) {
        const int colBase = slabBase + ch * 32;
#pragma unroll
        for (int i = 0; i < 8; ++i) {
            int u = i * 256 + tid;      // 0..2047
            int fmt = u >> 10;          // wave-uniform
            int u1 = u & 1023;
            int c2 = u1 >> 5, kgs = u1 & 31;
            int kg = kgs ^ c2;          // XOR swizzle
            const unsigned short* g =
                (fmt ? el : eh) + (size_t)(colBase + c2) * 256 + kg * 8;
            gload_lds16(g, smem + buf * 32768 + ((size_t)u << 4));
        }
    };

    stage(0, 0);
    __syncthreads();

    for (int ch = 0; ch < 64; ++ch) {
        const int cur = ch & 1;
        if (ch + 1 < 64) stage(cur ^ 1, ch + 1);  // async prefetch

        const float sec = se[slabBase + ch * 32 + col];

        f32x16 acc = {};
        const char* sp = smem + cur * 32768;
        const char* spl = sp + 16384;
#pragma unroll
        for (int ks = 0; ks < 16; ++ks) {
            const int a = BASE ^ (ks << 5);
            short8 Bh = *(const short8*)(sp + a);
            short8 Bl = *(const short8*)(spl + a);
            acc = __builtin_amdgcn_mfma_f32_32x32x16_bf16(Ah[ks], Bh, acc, 0, 0, 0);
            acc = __builtin_amdgcn_mfma_f32_32x32x16_bf16(Ah[ks], Bl, acc, 0, 0, 0);
            acc = __builtin_amdgcn_mfma_f32_32x32x16_bf16(Al[ks], Bh, acc, 0, 0, 0);
        }

        // d = fma(-2, dot, fl(sz+se)) == fl(fl(sz+se) - 2*dot) exactly.
        const int colg = slabBase + ch * 32 + col;
#pragma unroll
        for (int r = 0; r < 16; ++r) {
            float szse = __fadd_rn(szrow[r], sec);
            float d = fmaf(-2.0f, acc[r], szse);
            if (d < minv[r]) {          // strict <: first (lowest) col wins
                minv[r] = d;
                mini[r] = colg;
            }
        }
        __syncthreads();   // prefetch landed + cur consumed
    }

    // reduce across the 32 lanes (col) sharing each output row (same half)
#pragma unroll
    for (int st = 1; st < 32; st <<= 1) {
#pragma unroll
        for (int r = 0; r < 16; ++r) {
            float ov = __shfl_xor(minv[r], st);
            int oi = __shfl_xor(mini[r], st);
            if (ov < minv[r] || (ov == minv[r] && oi < mini[r])) {
                minv[r] = ov;
                mini[r] = oi;
            }
        }
    }
    if (col == 0) {
#pragma unroll
        for (int r = 0; r < 16; ++r) {
            int row = rowBase + (r & 3) + 8 * (r >> 2) + 4 * half;
            pval[(size_t)row * 8 + slab] = minv[r];
            pidx[(size_t)row * 8 + slab] = mini[r];
        }
    }
}

// ---------------------------------------------------------------- K3a:
// per-token: reduce 8 slab partials -> final index; rotation scalars;
// per-block loss partial.
__global__ __launch_bounds__(256) void k3a_token(
    const float* __restrict__ z_flat, const float* __restrict__ emb,
    const float* __restrict__ pval, const int* __restrict__ pidx,
    float* __restrict__ alpha, float* __restrict__ beta,
    int* __restrict__ idxf, float* __restrict__ out,
    float* __restrict__ lpart) {
    __shared__ float red[4];
    const int w = threadIdx.x >> 6, lane = threadIdx.x & 63;
    const int t = blockIdx.x * 4 + w;

    float bv = INFINITY;
    int bi = 0x7fffffff;
    if (lane < 8) {
        bv = pval[(size_t)t * 8 + lane];
        bi = pidx[(size_t)t * 8 + lane];
    }
#pragma unroll
    for (int st = 1; st < 8; st <<= 1) {
        float ov = __shfl_xor(bv, st);
        int oi = __shfl_xor(bi, st);
        if (ov < bv || (ov == bv && oi < bi)) { bv = ov; bi = oi; }
    }
    const int best = __shfl(bi, 0);

    const float4 zv = *(const float4*)(z_flat + (size_t)t * 256 + lane * 4);
    const float4 ev = *(const float4*)(emb + (size_t)best * 256 + lane * 4);
    float szs = zv.x * zv.x + zv.y * zv.y + zv.z * zv.z + zv.w * zv.w;
    float ses = ev.x * ev.x + ev.y * ev.y + ev.z * ev.z + ev.w * ev.w;
    float zes = zv.x * ev.x + zv.y * ev.y + zv.z * ev.z + zv.w * ev.w;
    float dx = zv.x - ev.x, dy = zv.y - ev.y, dz = zv.z - ev.z, dw = zv.w - ev.w;
    float sqs = dx * dx + dy * dy + dz * dz + dw * dw;
#pragma unroll
    for (int m = 1; m < 64; m <<= 1) {
        szs += __shfl_xor(szs, m);
        ses += __shfl_xor(ses, m);
        zes += __shfl_xor(zes, m);
        sqs += __shfl_xor(sqs, m);
    }
    if (lane == 0) {
        float ns = sqrtf(szs), nt = sqrtf(ses);
        float inv_s = 1.0f / (ns + EPSV);
        float inv_t = 1.0f / (nt + EPSV);
        float s2 = szs * inv_s;                      // z . u
        float su = szs * inv_s * inv_s;
        float sq = ses * inv_t * inv_t;
        float uq = zes * inv_s * inv_t;
        float nw = sqrtf(su + sq + 2.0f * uq);
        float inv_w = 1.0f / (nw + EPSV);
        float s1 = (s2 + zes * inv_t) * inv_w;       // z . w_
        float scale = nt * inv_s;
        float a = scale * (1.0f - 2.0f * s1 * inv_w * inv_s);
        float bb = scale * inv_t * 2.0f * (s2 - s1 * inv_w);
        alpha[t] = a;
        beta[t] = bb;
        idxf[t] = best;
        out[2097153 + t] = (float)best;
        red[w] = sqs;
    }
    __syncthreads();
    if (threadIdx.x == 0)
        lpart[blockIdx.x] = red[0] + red[1] + red[2] + red[3];
}

// ---------------------------------------------------------------- K4: loss
__global__ __launch_bounds__(256) void k4_loss(float* __restrict__ out,
                                               const float* __restrict__ lpart) {
    __shared__ float red[4];
    const int tid = threadIdx.x;
    float s = 0.0f;
    for (int i = tid; i < 2048; i += 256) s += lpart[i];
#pragma unroll
    for (int m = 1; m < 64; m <<= 1) s += __shfl_xor(s, m);
    if ((tid & 63) == 0) red[tid >> 6] = s;
    __syncthreads();
    if (tid == 0)
        out[2097152] = 1.25f * (red[0] + red[1] + red[2] + red[3]) *
                       (1.0f / 2097152.0f);
}

// ---------------------------------------------------------------- K3b:
// z_q[b][c][yx] = alpha[t]*z[b][c][yx] + beta[t]*emb[idx[t]][c]
__global__ __launch_bounds__(256) void k3b_zq(
    const float* __restrict__ zin, const float* __restrict__ emb,
    const float* __restrict__ alpha, const float* __restrict__ beta,
    const int* __restrict__ idxf, float* __restrict__ out) {
    const int i = blockIdx.x * 256 + threadIdx.x;
    const int c = (i >> 10) & 255;
    const int t = ((i >> 18) << 10) | (i & 1023);
    out[i] = alpha[t] * zin[i] + beta[t] * emb[(size_t)idxf[t] * 256 + c];
}

// ----------------------------------------------------------------
extern "C" void kernel_launch(void* const* d_in, const int* in_sizes, int n_in,
                              void* d_out, int out_size, void* d_ws,
                              size_t ws_size, hipStream_t stream) {
    (void)in_sizes; (void)n_in; (void)out_size; (void)ws_size;
    const float* zin = (const float*)d_in[0];
    const float* cb  = (const float*)d_in[1];
    const float* Wm  = (const float*)d_in[2];
    float* out = (float*)d_out;
    char* ws = (char*)d_ws;

    float*          z_flat = (float*)(ws + 0);                     //  8 MB
    unsigned short* zh     = (unsigned short*)(ws + 8388608);      //  4 MB
    unsigned short* zl     = (unsigned short*)(ws + 12582912);     //  4 MB
    float*          emb    = (float*)(ws + 16777216);              // 16 MB
    unsigned short* eh     = (unsigned short*)(ws + 33554432);     //  8 MB
    unsigned short* el     = (unsigned short*)(ws + 41943040);     //  8 MB
    float*          sz     = (float*)(ws + 50331648);              // 32 KB
    float*          se     = (float*)(ws + 50364416);              // 64 KB
    float*          pval   = (float*)(ws + 50429952);              // 256 KB
    int*            pidx   = (int*)(ws + 50692096);                // 256 KB
    float*          alpha  = (float*)(ws + 50954240);              // 32 KB
    float*          beta   = (float*)(ws + 50987008);              // 32 KB
    int*            idxf   = (int*)(ws + 51019776);                // 32 KB
    float*          lpart  = (float*)(ws + 51052544);              //  8 KB
    unsigned short* wh     = (unsigned short*)(ws + 51060736);     // 128 KB
    unsigned short* wl     = (unsigned short*)(ws + 51191808);     // 128 KB

    k0a_transpose<<<dim3(16, 4, 8), 256, 0, stream>>>(zin, z_flat, zh, zl);
    k0b_sz<<<2048, 256, 0, stream>>>(z_flat, sz);
    k0pre<<<64, 256, 0, stream>>>(Wm, wh, wl);
    k0c_emb<<<dim3(128, 2), 256, 0, stream>>>(cb, wh, wl, emb, eh, el);
    k0d_se<<<4096, 256, 0, stream>>>(emb, se);
    k1_dist_argmin<<<dim3(64, 8), 256, 0, stream>>>(zh, zl, eh, el, sz, se,
                                                    pval, pidx);
    k3a_token<<<2048, 256, 0, stream>>>(z_flat, emb, pval, pidx, alpha, beta,
                                        idxf, out, lpart);
    k4_loss<<<1, 256, 0, stream>>>(out, lpart);
    k3b_zq<<<8192, 256, 0, stream>>>(zin, emb, alpha, beta, idxf, out);
}